// Round 4
// baseline (727.884 us; speedup 1.0000x reference)
//
#include <hip/hip_runtime.h>

// Problem constants (from reference)
constexpr int T_FRAMES = 96;
constexpr int HH = 720;
constexpr int WW = 1280;
constexpr int HW = HH * WW;            // 921600
constexpr int N_NOISE = 10;

constexpr int PIX = 8;                 // pixels per thread (2x float4)
constexpr int BLOCK = 64;              // 1 wave per block
constexpr int NBLOCKS = HW / PIX / BLOCK;  // 1800 blocks = 1800 waves, ~7/CU, all resident

typedef float f4 __attribute__((ext_vector_type(4)));

// ---------------------------------------------------------------------------
// Noise-dtype detection (parallel, ~5 us): sample first 256 KiB of on_noise.
//   int32 0/1  : nonzero only at byte 0      -> b == 0            -> flag 0
//   float32 1.0: bytes 00 00 80 3f, byte0==0 -> a == 0            -> flag 2
//   uint8 0/1  : nonzero at all positions    -> a != 0 && b != 0  -> flag 1
// ---------------------------------------------------------------------------
constexpr int DET_BLOCKS = 64;         // 64*256*16B = 256 KiB sampled

__global__ __launch_bounds__(256)
void detect_noise_dtype(const uint4* __restrict__ noise,
                        unsigned int* __restrict__ counters) {
    const int i = blockIdx.x * 256 + threadIdx.x;
    const uint4 v = noise[i];
    unsigned a = 0, b = 0;
    const unsigned w[4] = {v.x, v.y, v.z, v.w};
#pragma unroll
    for (int k = 0; k < 4; ++k) {
        a += ((w[k] & 0x000000ffu) != 0);
        b += ((w[k] & 0x0000ff00u) != 0);
        b += ((w[k] & 0x00ff0000u) != 0);
        b += ((w[k] & 0xff000000u) != 0);
    }
    if (a) atomicAdd(&counters[0], a);
    if (b) atomicAdd(&counters[1], b);
}

// Load 8 bools at element index idx (multiple of 8) -> 8-bit mask.
template <int FLAG>
__device__ __forceinline__ unsigned pack8(const void* __restrict__ p, int idx) {
    if (FLAG == 1) {
        const uint2 v = *reinterpret_cast<const uint2*>(
            reinterpret_cast<const unsigned char*>(p) + idx);
        unsigned m = 0;
#pragma unroll
        for (int k = 0; k < 4; ++k) {
            m |= ((v.x >> (8 * k)) & 0xffu) ? (1u << k)       : 0u;
            m |= ((v.y >> (8 * k)) & 0xffu) ? (1u << (k + 4)) : 0u;
        }
        return m;
    } else if (FLAG == 0) {
        const int4 a = *(reinterpret_cast<const int4*>(
            reinterpret_cast<const int*>(p) + idx));
        const int4 b = *(reinterpret_cast<const int4*>(
            reinterpret_cast<const int*>(p) + idx) + 1);
        return (a.x ? 1u : 0u)  | (a.y ? 2u : 0u)  | (a.z ? 4u : 0u)  | (a.w ? 8u : 0u) |
               (b.x ? 16u : 0u) | (b.y ? 32u : 0u) | (b.z ? 64u : 0u) | (b.w ? 128u : 0u);
    } else {
        const float4 a = *(reinterpret_cast<const float4*>(
            reinterpret_cast<const float*>(p) + idx));
        const float4 b = *(reinterpret_cast<const float4*>(
            reinterpret_cast<const float*>(p) + idx) + 1);
        return (a.x != 0.f ? 1u : 0u)  | (a.y != 0.f ? 2u : 0u)  |
               (a.z != 0.f ? 4u : 0u)  | (a.w != 0.f ? 8u : 0u)  |
               (b.x != 0.f ? 16u : 0u) | (b.y != 0.f ? 32u : 0u) |
               (b.z != 0.f ? 64u : 0u) | (b.w != 0.f ? 128u : 0u);
    }
}

__device__ __forceinline__ float classify(float cur, float prev,
                                          unsigned on, unsigned off) {
    const float d = cur - prev;
    float o = (d == 0.f) ? 127.f : (d > 0.f ? 255.f : 0.f);
    if (on)  o = 255.f;   // on-noise forces 255 ...
    if (off) o = 0.f;     // ... but off-noise wins (matches reference nesting)
    return o;
}

__device__ __forceinline__ f4 classify4(f4 cur, f4 prev, unsigned mon, unsigned moff) {
    f4 o;
    o.x = classify(cur.x, prev.x, mon & 1u, moff & 1u);
    o.y = classify(cur.y, prev.y, mon & 2u, moff & 2u);
    o.z = classify(cur.z, prev.z, mon & 4u, moff & 4u);
    o.w = classify(cur.w, prev.w, mon & 8u, moff & 8u);
    return o;
}

template <int FLAG>
__device__ void neuro_body(const float* __restrict__ tensor,
                           const float* __restrict__ state,
                           const void* __restrict__ on_noise,
                           const void* __restrict__ off_noise,
                           float* __restrict__ out) {
    const int p = (blockIdx.x * BLOCK + threadIdx.x) * PIX;

    // Prefetch + bit-pack ALL noise for this thread's 8 pixels:
    // byte ni of {onb0:onb1} = 8-bit mask for noise[ni][p..p+7]. 80 bits each.
    unsigned long long onb0 = 0, onb1 = 0, offb0 = 0, offb1 = 0;
#pragma unroll
    for (int ni = 0; ni < 8; ++ni) {
        onb0  |= (unsigned long long)pack8<FLAG>(on_noise,  ni * HW + p) << (ni * 8);
        offb0 |= (unsigned long long)pack8<FLAG>(off_noise, ni * HW + p) << (ni * 8);
    }
#pragma unroll
    for (int ni = 8; ni < N_NOISE; ++ni) {
        onb1  |= (unsigned long long)pack8<FLAG>(on_noise,  ni * HW + p) << ((ni - 8) * 8);
        offb1 |= (unsigned long long)pack8<FLAG>(off_noise, ni * HW + p) << ((ni - 8) * 8);
    }

    f4 prev0 = *reinterpret_cast<const f4*>(state + p);
    f4 prev1 = *reinterpret_cast<const f4*>(state + p + 4);
    const float* tp = tensor + p;
    float*       op = out + p;

    int ni = 1;                                          // cnt % N_NOISE at t=0
#pragma unroll 4
    for (int t = 0; t < T_FRAMES; ++t) {
        const f4 cur0 = __builtin_nontemporal_load(reinterpret_cast<const f4*>(tp));
        const f4 cur1 = __builtin_nontemporal_load(reinterpret_cast<const f4*>(tp + 4));

        // ni is wave-uniform -> uniform select + 64-bit shift (cheap)
        const unsigned mon  = (unsigned)((ni < 8) ? (onb0  >> (ni * 8))
                                                  : (onb1  >> ((ni - 8) * 8))) & 0xffu;
        const unsigned moff = (unsigned)((ni < 8) ? (offb0 >> (ni * 8))
                                                  : (offb1 >> ((ni - 8) * 8))) & 0xffu;

        const f4 o0 = classify4(cur0, prev0, mon, moff);
        const f4 o1 = classify4(cur1, prev1, mon >> 4, moff >> 4);

        __builtin_nontemporal_store(o0, reinterpret_cast<f4*>(op));
        __builtin_nontemporal_store(o1, reinterpret_cast<f4*>(op + 4));
        prev0 = cur0;
        prev1 = cur1;
        tp += HW;
        op += HW;
        ni = (ni == N_NOISE - 1) ? 0 : ni + 1;           // uniform update
    }
}

__global__ __launch_bounds__(BLOCK)
void neuro_kernel(const float* __restrict__ tensor,
                  const float* __restrict__ state,
                  const void* __restrict__ on_noise,
                  const void* __restrict__ off_noise,
                  float* __restrict__ out,
                  const unsigned int* __restrict__ counters) {
    const unsigned a = counters[0], b = counters[1];
    const int flag = (b == 0u) ? 0 : ((a == 0u) ? 2 : 1);   // wave-uniform
    if (flag == 1)      neuro_body<1>(tensor, state, on_noise, off_noise, out);
    else if (flag == 0) neuro_body<0>(tensor, state, on_noise, off_noise, out);
    else                neuro_body<2>(tensor, state, on_noise, off_noise, out);
}

extern "C" void kernel_launch(void* const* d_in, const int* in_sizes, int n_in,
                              void* d_out, int out_size, void* d_ws, size_t ws_size,
                              hipStream_t stream) {
    const float* tensor   = (const float*)d_in[0];   // (T,H,W) f32
    const float* state    = (const float*)d_in[1];   // (H,W) f32
    // d_in[2] = timesurface (H,W) f32 — provably unused (refractory is a no-op)
    const void*  on_noise  = d_in[3];                // (N_NOISE,H,W) bool
    const void*  off_noise = d_in[4];                // (N_NOISE,H,W) bool
    float* out = (float*)d_out;                      // (T,H,W) f32
    unsigned int* counters = (unsigned int*)d_ws;    // [a, b]

    hipMemsetAsync(counters, 0, 2 * sizeof(unsigned int), stream);

    detect_noise_dtype<<<DET_BLOCKS, 256, 0, stream>>>(
        (const uint4*)on_noise, counters);

    neuro_kernel<<<NBLOCKS, BLOCK, 0, stream>>>(
        tensor, state, on_noise, off_noise, out, counters);
}